// Round 10
// baseline (144.870 us; speedup 1.0000x reference)
//
#include <hip/hip_runtime.h>
#include <hip/hip_bf16.h>

#define SEQ    2048
#define DMODEL 1024
#define HEADS  16
#define DHEAD  64
#define BATCH  2
#define TOK    (BATCH * SEQ)    // 4096
#define NQKV   (3 * DMODEL)     // 3072
#define QK_SCALE (0.125f * 1.4426950408889634f)   // fold DH^-0.5 and log2(e) into q

typedef __attribute__((ext_vector_type(8))) short bf16x8;
typedef __attribute__((ext_vector_type(4))) float f32x4;

__device__ __forceinline__ float bf2f(ushort u) {
  union { unsigned int i; float f; } v; v.i = ((unsigned int)u) << 16; return v.f;
}
__device__ __forceinline__ ushort f2bf(float f) {
  union { float f; unsigned int i; } v; v.f = f;
  unsigned int r = (v.i + 0x7fffu + ((v.i >> 16) & 1u)) >> 16;
  return (ushort)r;
}

// XOR-swizzle for [row][128-byte-row] LDS tiles: spreads 16B slots across banks.
__device__ __forceinline__ int swz(int row, int byteoff) {
  return row * 128 + (byteoff ^ ((row & 7) << 4));
}
// K-row permutation (attn): LDS slot s = nf*16+g*4+r holds global kv row
// pi(s) = nf1*32 + g*8 + nf0*4 + r  -> lane (g) ends up holding exactly kv
// {g*8..g*8+7} u {32+g*8..+7}: the PV A-fragment, with no cross-lane traffic.
__device__ __forceinline__ int kperm(int s) {
  return (s & 0x20) | ((s & 0x0C) << 1) | ((s & 0x10) >> 2) | (s & 3);
}

#define GLL16(g, l)                                                                     \
  __builtin_amdgcn_global_load_lds((const __attribute__((address_space(1))) void*)(g),  \
                                   (__attribute__((address_space(3))) void*)(l), 16, 0, 0)

// ---------------- LayerNorm: fp32 in -> bf16 out, one block per token ----------------
__global__ __launch_bounds__(256) void ln_kernel(const float* __restrict__ x,
                                                 const float* __restrict__ g,
                                                 const float* __restrict__ b,
                                                 ushort* __restrict__ xn) {
  int t = blockIdx.x;
  int tid = threadIdx.x;
  const float* row = x + (size_t)t * DMODEL;
  float4 v = *(const float4*)(row + tid * 4);
  float s  = v.x + v.y + v.z + v.w;
  float s2 = v.x * v.x + v.y * v.y + v.z * v.z + v.w * v.w;
#pragma unroll
  for (int m = 32; m >= 1; m >>= 1) {
    s  += __shfl_down(s, m);
    s2 += __shfl_down(s2, m);
  }
  __shared__ float ws[4], ws2[4];
  if ((tid & 63) == 0) { ws[tid >> 6] = s; ws2[tid >> 6] = s2; }
  __syncthreads();
  s  = ws[0] + ws[1] + ws[2] + ws[3];
  s2 = ws2[0] + ws2[1] + ws2[2] + ws2[3];
  float mu  = s * (1.f / DMODEL);
  float var = s2 * (1.f / DMODEL) - mu * mu;
  float rs  = rsqrtf(var + 1e-5f);
  float4 gv = *(const float4*)(g + tid * 4);
  float4 bv = *(const float4*)(b + tid * 4);
  ushort4 o;
  o.x = f2bf((v.x - mu) * rs * gv.x + bv.x);
  o.y = f2bf((v.y - mu) * rs * gv.y + bv.y);
  o.z = f2bf((v.z - mu) * rs * gv.z + bv.z);
  o.w = f2bf((v.w - mu) * rs * gv.w + bv.w);
  *(ushort4*)(xn + (size_t)t * DMODEL + tid * 4) = o;
}

// ---------------- fp32 [R][C] -> bf16 [C][R] transpose ----------------
__global__ void transpose_f2b(const float* __restrict__ in, ushort* __restrict__ out,
                              int R, int C) {
  __shared__ float tile[32][33];
  int c0 = blockIdx.x * 32, r0 = blockIdx.y * 32;
  int x = threadIdx.x, y = threadIdx.y;
#pragma unroll
  for (int i = 0; i < 32; i += 8) tile[y + i][x] = in[(size_t)(r0 + y + i) * C + c0 + x];
  __syncthreads();
#pragma unroll
  for (int i = 0; i < 32; i += 8) out[(size_t)(c0 + y + i) * R + r0 + x] = f2bf(tile[x][y + i]);
}

// ---------------- RoPE cos/sin tables [SEQ][DHEAD] fp32 ----------------
__global__ void rope_tab_kernel(float* __restrict__ ct, float* __restrict__ st) {
  int n = blockIdx.x, d = threadIdx.x;
  float invf = expf(-logf(10000.f) * (float)(d & 31) * (1.f / 32.f));
  float a = (float)n * invf;
  ct[n * DHEAD + d] = cosf(a);
  st[n * DHEAD + d] = sinf(a);
}

// ==== QKV GEMM, 8-phase 256^2 schedule (T2+T3+T4+T5) ====
// 512 thr = 8 waves (2M x 4N), per-wave 128x64 out, BK=64, 2 K-tiles buffered.
// Per K-tile: 4 phases {stage half-tile; ds_read quadrant(+B in ph0); lgkm0;
// MFMA x16; barrier}. B regs cached after ph0 -> B(kt+2) restages same buffer
// at ph2/ph3. A(kt+1) stages at ph0/ph1 into the buffer freed by kt-1.
// Counted vmcnt(4) at K-tile boundary only (never 0 in steady state).
// LDS slot^(row&7) swizzle; source pre-swizzled (gll16 dest linear).
// Epilogue: RoPE + head-scatter, q pre-scaled for exp2.
__global__ __launch_bounds__(512, 2) void gemm_qkv_8p(const ushort* __restrict__ A,
                                                      const ushort* __restrict__ BT,
                                                      ushort* __restrict__ qh,
                                                      ushort* __restrict__ kh,
                                                      ushort* __restrict__ vh,
                                                      const float* __restrict__ ct,
                                                      const float* __restrict__ st,
                                                      int M, int N, int K) {
  extern __shared__ ushort smem[];   // [A0 16K][A1 16K][B0 16K][B1 16K] ushorts
  int tid = threadIdx.x;
  int wid = tid >> 6, lane = tid & 63;
  int wm = wid >> 2, wn = wid & 3;
  int lrow = lane & 15, g = lane >> 4;
  int m0 = blockIdx.y * 256, n0 = blockIdx.x * 256;
  int rr = tid >> 3, sl = tid & 7;
  int ss = sl ^ (rr & 7);              // pre-swizzled source slot (involution)
  int nk = K >> 6;
  f32x4 acc[8][4] = {};

#define STA8(dst, kt, h, j)                                                         \
  GLL16(A + (size_t)(m0 + (h) * 128 + (j) * 64 + rr) * K + (kt) * 64 + ss * 8,      \
        (dst) + ((h) * 128 + (j) * 64 + rr) * 64 + sl * 8)
#define STB8(dst, kt, h, j)                                                         \
  GLL16(BT + (size_t)(n0 + (h) * 128 + (j) * 64 + rr) * K + (kt) * 64 + ss * 8,     \
        (dst) + ((h) * 128 + (j) * 64 + rr) * 64 + sl * 8)
#define BARR() asm volatile("s_barrier" ::: "memory")

  // prologue: stage B0, A0, B1; wait until A0,B0 landed (B1's 4 stay in flight)
  {
    ushort* b0 = smem + 32768;
    ushort* b1 = smem + 49152;
    ushort* a0 = smem;
    STB8(b0, 0, 0, 0); STB8(b0, 0, 0, 1); STB8(b0, 0, 1, 0); STB8(b0, 0, 1, 1);
    STA8(a0, 0, 0, 0); STA8(a0, 0, 0, 1); STA8(a0, 0, 1, 0); STA8(a0, 0, 1, 1);
    STB8(b1, 1, 0, 0); STB8(b1, 1, 0, 1); STB8(b1, 1, 1, 0); STB8(b1, 1, 1, 1);
  }
  asm volatile("s_waitcnt vmcnt(4)" ::: "memory");
  BARR();
  __builtin_amdgcn_sched_barrier(0);

  for (int kt = 0; kt < nk; ++kt) {
    const ushort* Ar = smem + ((kt & 1) << 14);
    ushort* Asn = smem + (((kt + 1) & 1) << 14);          // A(kt+1) target
    ushort* Br  = smem + 32768 + ((kt & 1) << 14);        // read + B(kt+2) target
    bf16x8 brf[4][2];
#pragma unroll
    for (int q = 0; q < 4; ++q) {
      // ---- stage one half-tile (issue first, fly under compute)
      if (q == 0)      { if (kt + 1 < nk) { STA8(Asn, kt + 1, 0, 0); STA8(Asn, kt + 1, 0, 1); } }
      else if (q == 1) { if (kt + 1 < nk) { STA8(Asn, kt + 1, 1, 0); STA8(Asn, kt + 1, 1, 1); } }
      else if (q == 2) { if (kt + 2 < nk) { STB8(Br, kt + 2, 0, 0); STB8(Br, kt + 2, 0, 1); } }
      else             { if (kt + 2 < nk) { STB8(Br, kt + 2, 1, 0); STB8(Br, kt + 2, 1, 1); } }
      // ---- ds_read: B frags once (phase 0), A quadrant each phase
      if (q == 0) {
#pragma unroll
        for (int nf = 0; nf < 4; ++nf)
#pragma unroll
          for (int ks = 0; ks < 2; ++ks) {
            int r = wn * 64 + nf * 16 + lrow;
            brf[nf][ks] = *(const bf16x8*)((const char*)Br + r * 128 +
                                           ((ks * 64 + g * 16) ^ ((r & 7) << 4)));
          }
      }
      bf16x8 arf[2][2];
#pragma unroll
      for (int i = 0; i < 2; ++i)
#pragma unroll
        for (int ks = 0; ks < 2; ++ks) {
          int r = wm * 128 + (2 * q + i) * 16 + lrow;
          arf[i][ks] = *(const bf16x8*)((const char*)Ar + r * 128 +
                                        ((ks * 64 + g * 16) ^ ((r & 7) << 4)));
        }
      asm volatile("s_waitcnt lgkmcnt(0)" ::: "memory");
      __builtin_amdgcn_sched_barrier(0);
      __builtin_amdgcn_s_setprio(1);
#pragma unroll
      for (int ks = 0; ks < 2; ++ks)
#pragma unroll
        for (int i = 0; i < 2; ++i)
#pragma unroll
          for (int nf = 0; nf < 4; ++nf)
            acc[2 * q + i][nf] = __builtin_amdgcn_mfma_f32_16x16x32_bf16(
                arf[i][ks], brf[nf][ks], acc[2 * q + i][nf], 0, 0, 0);
      __builtin_amdgcn_s_setprio(0);
      if (q < 3) BARR();
    }
    // K-tile boundary: everything up to A(kt+1) must be landed; B(kt+2)'s 4
    // loads (the newest) may stay in flight.
    if (kt + 2 < nk) asm volatile("s_waitcnt vmcnt(4)" ::: "memory");
    else             asm volatile("s_waitcnt vmcnt(0)" ::: "memory");
    BARR();
    __builtin_amdgcn_sched_barrier(0);
  }
#undef STA8
#undef STB8
#undef BARR

  // ---- epilogue: RoPE + head scatter
#pragma unroll
  for (int mf = 0; mf < 8; ++mf)
#pragma unroll
    for (int nf = 0; nf < 4; ++nf) {
      int col = n0 + wn * 64 + nf * 16 + lrow;
      int mat = col >> 10, c1 = col & 1023;
      int h = c1 >> 6, d = c1 & 63;
#pragma unroll
      for (int r = 0; r < 4; ++r) {
        int rowi = m0 + wm * 128 + mf * 16 + g * 4 + r;
        int bb = rowi >> 11, n = rowi & (SEQ - 1);
        float val = acc[mf][nf][r];
        if (mat < 2) {
          float partner = acc[mf][nf ^ 2][r];   // col ^ 32 lives in the same lane
          float cs = ct[n * DHEAD + d], sn = st[n * DHEAD + d];
          float sgn = (d & 32) ? 1.f : -1.f;
          val = val * cs + sgn * partner * sn;
          if (mat == 0) val *= QK_SCALE;
        }
        ushort* dst = (mat == 0) ? qh : (mat == 1) ? kh : vh;
        dst[((size_t)(bb * HEADS + h) * SEQ + n) * DHEAD + d] = f2bf(val);
      }
    }
}

// ---- out-proj GEMM: rd6 2-phase 128^2 structure (256 blocks, full CU util) ----
__global__ __launch_bounds__(256) void gemm_out(const ushort* __restrict__ A,
                                                const ushort* __restrict__ BT,
                                                float* __restrict__ Cf,
                                                const float* __restrict__ bias,
                                                int M, int N, int K) {
  __shared__ __align__(16) ushort As[128 * 32];
  __shared__ __align__(16) ushort Bs[128 * 32];
  int tid = threadIdx.x;
  int w = tid >> 6, lane = tid & 63;
  int lrow = lane & 15, g = lane >> 4;
  int m0 = blockIdx.y * 128, n0 = blockIdx.x * 128;
  int wr = (w >> 1) * 64, wc = (w & 1) * 64;
  int grow = lane >> 2;
  int gcol = ((lane & 3) ^ ((grow >> 1) & 3)) * 8;
  ushort* ldsA0 = As + w * 512;
  ushort* ldsA1 = As + 2048 + w * 512;
  ushort* ldsB0 = Bs + w * 512;
  ushort* ldsB1 = Bs + 2048 + w * 512;
  int fcol = (g ^ ((lrow >> 1) & 3)) * 8;
  f32x4 acc[4][4] = {};
  for (int k0 = 0; k0 < K; k0 += 32) {
    __syncthreads();
    GLL16(A  + (size_t)(m0 + w * 16 + grow) * K + k0 + gcol, ldsA0);
    GLL16(A  + (size_t)(m0 + 64 + w * 16 + grow) * K + k0 + gcol, ldsA1);
    GLL16(BT + (size_t)(n0 + w * 16 + grow) * K + k0 + gcol, ldsB0);
    GLL16(BT + (size_t)(n0 + 64 + w * 16 + grow) * K + k0 + gcol, ldsB1);
    __syncthreads();
    bf16x8 af[4], bfr[4];
#pragma unroll
    for (int i = 0; i < 4; i++) af[i]  = *(const bf16x8*)(As + (wr + i * 16 + lrow) * 32 + fcol);
#pragma unroll
    for (int i = 0; i < 4; i++) bfr[i] = *(const bf16x8*)(Bs + (wc + i * 16 + lrow) * 32 + fcol);
    __builtin_amdgcn_s_setprio(1);
#pragma unroll
    for (int mf = 0; mf < 4; mf++)
#pragma unroll
      for (int nf = 0; nf < 4; nf++)
        acc[mf][nf] = __builtin_amdgcn_mfma_f32_16x16x32_bf16(af[mf], bfr[nf], acc[mf][nf], 0, 0, 0);
    __builtin_amdgcn_s_setprio(0);
  }
#pragma unroll
  for (int mf = 0; mf < 4; mf++)
#pragma unroll
    for (int nf = 0; nf < 4; nf++) {
      int col = n0 + wc + nf * 16 + lrow;
#pragma unroll
      for (int r = 0; r < 4; r++) {
        int rowi = m0 + wr + mf * 16 + g * 4 + r;
        Cf[(size_t)rowi * N + col] = acc[mf][nf][r] + bias[col];
      }
    }
}

// ---------------- causal flash attention (rd9 structure, unchanged) ----------------
__global__ __launch_bounds__(256) void attn_kernel(const ushort* __restrict__ q,
                                                   const ushort* __restrict__ k,
                                                   const ushort* __restrict__ v,
                                                   ushort* __restrict__ ao) {
  int wgid = blockIdx.x + gridDim.x * blockIdx.y;   // 0..1023
  int xcd = wgid & 7, idx = wgid >> 3;
  int bh = xcd * 4 + (idx & 3);          // 4 heads per XCD (K+V 2MB fits L2)
  int qt = 31 - (idx >> 2);              // big q-tiles dispatch first
  int tid = threadIdx.x, w = tid >> 6, lane = tid & 63;
  int lrow = lane & 15, g = lane >> 4;
  __shared__ __align__(16) ushort Ks[2][64 * 64];
  __shared__ __align__(16) ushort Vt[2][64 * 64];
  const ushort* qb = q + (size_t)bh * SEQ * DHEAD;
  const ushort* kb = k + (size_t)bh * SEQ * DHEAD;
  const ushort* vb = v + (size_t)bh * SEQ * DHEAD;
  const ushort* qp = qb + (size_t)(qt * 64 + w * 16 + lrow) * DHEAD + g * 8;
  bf16x8 qf0 = *(const bf16x8*)(qp), qf1 = *(const bf16x8*)(qp + 32);
  f32x4 aO[4] = {};
  float l_s = 0.f;

  int krow = tid >> 2, kco = (tid & 3) * 16;
  int pik = kperm(krow);
  int d0 = (tid & 31) * 2, kv8 = (tid >> 5) * 8;
  int4 ka0, ka1;
  unsigned int vd[8];

#define STAGE_ISSUE(j)                                                          \
  {                                                                             \
    const ushort* ks = kb + ((size_t)((j) * 64 + pik)) * DHEAD + kco;           \
    ka0 = *(const int4*)ks;                                                     \
    ka1 = *(const int4*)(ks + 8);                                               \
    const ushort* vs = vb + ((size_t)((j) * 64 + kv8)) * DHEAD + d0;            \
    _Pragma("unroll")                                                           \
    for (int jj = 0; jj < 8; jj++) vd[jj] = *(const unsigned int*)(vs + jj * DHEAD); \
  }

#define STAGE_WRITE(bsel)                                                       \
  {                                                                             \
    char* kd = (char*)Ks[bsel];                                                 \
    *(int4*)(kd + swz(krow, (tid & 3) * 32)) = ka0;                             \
    *(int4*)(kd + swz(krow, (tid & 3) * 32 + 16)) = ka1;                        \
    unsigned int lo[4], hi[4];                                                  \
    _Pragma("unroll")                                                           \
    for (int jj = 0; jj < 4; jj++) {                                            \
      lo[jj] = __builtin_amdgcn_perm(vd[2 * jj + 1], vd[2 * jj], 0x05040100u);  \
      hi[jj] = __builtin_amdgcn_perm(vd[2 * jj + 1], vd[2 * jj], 0x07060302u);  \
    }                                                                           \
    char* vdst = (char*)Vt[bsel];                                               \
    *(int4*)(vdst + swz(d0, kv8 * 2))     = *(int4*)lo;                         \
    *(int4*)(vdst + swz(d0 + 1, kv8 * 2)) = *(int4*)hi;                         \
  }

  STAGE_ISSUE(0);
  STAGE_WRITE(0);
  __syncthreads();
  int cur = 0;

  for (int jt = 0; jt <= qt; jt++) {
    if (jt < qt) STAGE_ISSUE(jt + 1);
    const char* kbuf = (const char*)Ks[cur];
    const char* vbuf = (const char*)Vt[cur];
    bf16x8 kf[8];
#pragma unroll
    for (int nf = 0; nf < 4; nf++) {
      kf[2 * nf]     = *(const bf16x8*)(kbuf + swz(nf * 16 + lrow, g * 16));
      kf[2 * nf + 1] = *(const bf16x8*)(kbuf + swz(nf * 16 + lrow, g * 16 + 64));
    }
    bf16x8 pa0, pa1;
    {
      f32x4 aS[4] = {};
      __builtin_amdgcn_s_setprio(1);
#pragma unroll
      for (int nf = 0; nf < 4; nf++) {
        aS[nf] = __builtin_amdgcn_mfma_f32_16x16x32_bf16(kf[2 * nf], qf0, aS[nf], 0, 0, 0);
        aS[nf] = __builtin_amdgcn_mfma_f32_16x16x32_bf16(kf[2 * nf + 1], qf1, aS[nf], 0, 0, 0);
      }
      __builtin_amdgcn_s_setprio(0);
      union { bf16x8 v; __hip_bfloat162 h[4]; } a0, a1;
      bool diag = (jt == qt);
#pragma unroll
      for (int nf = 0; nf < 4; nf++) {
        float p[4];
#pragma unroll
        for (int r = 0; r < 4; r++) {
          int kvl = (nf >> 1) * 32 + g * 8 + (nf & 1) * 4 + r;
          p[r] = exp2f(aS[nf][r]);
          if (diag && kvl > w * 16 + lrow) p[r] = 0.f;
          l_s += p[r];
        }
        __hip_bfloat162 plo = __float22bfloat162_rn({p[0], p[1]});
        __hip_bfloat162 phi = __float22bfloat162_rn({p[2], p[3]});
        if (nf < 2) { a0.h[(nf & 1) * 2] = plo; a0.h[(nf & 1) * 2 + 1] = phi; }
        else        { a1.h[(nf & 1) * 2] = plo; a1.h[(nf & 1) * 2 + 1] = phi; }
      }
      pa0 = a0.v; pa1 = a1.v;
    }
    bf16x8 vf[8];
#pragma unroll
    for (int nf = 0; nf < 4; nf++) {
      vf[2 * nf]     = *(const bf16x8*)(vbuf + swz(nf * 16 + lrow, g * 16));
      vf[2 * nf + 1] = *(const bf16x8*)(vbuf + swz(nf * 16 + lrow, g * 16 + 64));
    }
    __builtin_amdgcn_s_setprio(1);
#pragma unroll
    for (int nf = 0; nf < 4; nf++) {
      aO[nf] = __builtin_amdgcn_mfma_f32_16x16x32_bf16(pa0, vf[2 * nf], aO[nf], 0, 0, 0);
      aO[nf] = __builtin_amdgcn_mfma_f32_16x16x32_bf16(pa1, vf[2 * nf + 1], aO[nf], 0, 0, 0);
    }
    __builtin_amdgcn_s_setprio(0);
    if (jt < qt) STAGE_WRITE(cur ^ 1);
    __syncthreads();
    cur ^= 1;
  }

  l_s += __shfl_xor(l_s, 16);
  l_s += __shfl_xor(l_s, 32);
  int b = bh >> 4, h = bh & 15;
#pragma unroll
  for (int r = 0; r < 4; r++) {
    float inv = 1.f / __shfl(l_s, g * 4 + r);
#pragma unroll
    for (int nf = 0; nf < 4; nf++) {
      int col = h * DHEAD + nf * 16 + lrow;
      int tok = b * SEQ + qt * 64 + w * 16 + g * 4 + r;
      ao[(size_t)tok * DMODEL + col] = f2bf(aO[nf][r] * inv);
    }
  }
#undef STAGE_ISSUE
#undef STAGE_WRITE
}

extern "C" void kernel_launch(void* const* d_in, const int* in_sizes, int n_in,
                              void* d_out, int out_size, void* d_ws, size_t ws_size,
                              hipStream_t stream) {
  const float* x    = (const float*)d_in[0];
  const float* Wqkv = (const float*)d_in[1];
  const float* Wout = (const float*)d_in[2];
  const float* bout = (const float*)d_in[3];
  const float* lng  = (const float*)d_in[4];
  const float* lnb  = (const float*)d_in[5];
  float* out = (float*)d_out;

  ushort* xn    = (ushort*)d_ws;                       // reused as ao after QKV GEMM
  ushort* WqkvT = xn + (size_t)TOK * DMODEL;
  ushort* WoutT = WqkvT + (size_t)NQKV * DMODEL;
  ushort* qh    = WoutT + (size_t)DMODEL * DMODEL;
  ushort* kh    = qh + (size_t)BATCH * HEADS * SEQ * DHEAD;
  ushort* vh    = kh + (size_t)BATCH * HEADS * SEQ * DHEAD;
  float*  ct    = (float*)(vh + (size_t)BATCH * HEADS * SEQ * DHEAD);
  float*  st    = ct + SEQ * DHEAD;
  ushort* ao    = xn;

  hipLaunchKernelGGL(ln_kernel, dim3(TOK), dim3(256), 0, stream, x, lng, lnb, xn);
  hipLaunchKernelGGL(transpose_f2b, dim3(NQKV / 32, DMODEL / 32), dim3(32, 8), 0, stream,
                     Wqkv, WqkvT, DMODEL, NQKV);
  hipLaunchKernelGGL(transpose_f2b, dim3(DMODEL / 32, DMODEL / 32), dim3(32, 8), 0, stream,
                     Wout, WoutT, DMODEL, DMODEL);
  hipLaunchKernelGGL(rope_tab_kernel, dim3(SEQ), dim3(DHEAD), 0, stream, ct, st);
  hipLaunchKernelGGL(gemm_qkv_8p, dim3(NQKV / 256, TOK / 256), dim3(512), 131072, stream,
                     xn, WqkvT, qh, kh, vh, ct, st, TOK, NQKV, DMODEL);
  hipLaunchKernelGGL(attn_kernel, dim3(32, 32), dim3(256), 0, stream,
                     qh, kh, vh, ao);
  hipLaunchKernelGGL(gemm_out, dim3(DMODEL / 128, TOK / 128), dim3(256), 0, stream,
                     ao, WoutT, out, bout, TOK, DMODEL, DMODEL);
}

// Round 11
// 124.636 us; speedup vs baseline: 1.1623x; 1.1623x over previous
//
#include <hip/hip_runtime.h>
#include <hip/hip_bf16.h>

#define SEQ    2048
#define DMODEL 1024
#define HEADS  16
#define DHEAD  64
#define BATCH  2
#define TOK    (BATCH * SEQ)    // 4096
#define NQKV   (3 * DMODEL)     // 3072
#define QK_SCALE (0.125f * 1.4426950408889634f)   // fold DH^-0.5 and log2(e) into q

typedef __attribute__((ext_vector_type(8))) short bf16x8;
typedef __attribute__((ext_vector_type(4))) float f32x4;

__device__ __forceinline__ float bf2f(ushort u) {
  union { unsigned int i; float f; } v; v.i = ((unsigned int)u) << 16; return v.f;
}
__device__ __forceinline__ ushort f2bf(float f) {
  union { float f; unsigned int i; } v; v.f = f;
  unsigned int r = (v.i + 0x7fffu + ((v.i >> 16) & 1u)) >> 16;
  return (ushort)r;
}

// XOR-swizzle for [row][128-byte-row] LDS tiles (attn): spreads 16B slots across banks.
__device__ __forceinline__ int swz(int row, int byteoff) {
  return row * 128 + (byteoff ^ ((row & 7) << 4));
}
// K-row permutation (attn): LDS slot s = nf*16+g*4+r holds global kv row
// pi(s) = nf1*32 + g*8 + nf0*4 + r  -> lane (g) ends up holding exactly kv
// {g*8..g*8+7} u {32+g*8..+7}: the PV A-fragment, with no cross-lane traffic.
__device__ __forceinline__ int kperm(int s) {
  return (s & 0x20) | ((s & 0x0C) << 1) | ((s & 0x10) >> 2) | (s & 3);
}

#define GLL16(g, l)                                                                     \
  __builtin_amdgcn_global_load_lds((const __attribute__((address_space(1))) void*)(g),  \
                                   (__attribute__((address_space(3))) void*)(l), 16, 0, 0)

// ---------------- fused prep: LN + W transposes + RoPE tables, one launch ----------
// Block ranges: [0,4096) LN rows; [4096,7168) Wqkv transpose 32x32 tiles;
// [7168,8192) Wout transpose; [8192,8704) RoPE table rows (4 per block).
#define PREP_LN    TOK
#define PREP_T1    (PREP_LN + (NQKV / 32) * (DMODEL / 32))
#define PREP_T2    (PREP_T1 + (DMODEL / 32) * (DMODEL / 32))
#define PREP_TOTAL (PREP_T2 + SEQ / 4)

__global__ __launch_bounds__(256) void prep_kernel(const float* __restrict__ x,
                                                   const float* __restrict__ lng,
                                                   const float* __restrict__ lnb,
                                                   ushort* __restrict__ xn,
                                                   const float* __restrict__ Wqkv,
                                                   ushort* __restrict__ WqkvT,
                                                   const float* __restrict__ Wout,
                                                   ushort* __restrict__ WoutT,
                                                   float* __restrict__ ct,
                                                   float* __restrict__ st) {
  int bid = blockIdx.x;
  int tid = threadIdx.x;
  if (bid < PREP_LN) {
    // ---- LayerNorm: one block per token
    int t = bid;
    const float* row = x + (size_t)t * DMODEL;
    float4 v = *(const float4*)(row + tid * 4);
    float s  = v.x + v.y + v.z + v.w;
    float s2 = v.x * v.x + v.y * v.y + v.z * v.z + v.w * v.w;
#pragma unroll
    for (int m = 32; m >= 1; m >>= 1) {
      s  += __shfl_down(s, m);
      s2 += __shfl_down(s2, m);
    }
    __shared__ float ws[4], ws2[4];
    if ((tid & 63) == 0) { ws[tid >> 6] = s; ws2[tid >> 6] = s2; }
    __syncthreads();
    s  = ws[0] + ws[1] + ws[2] + ws[3];
    s2 = ws2[0] + ws2[1] + ws2[2] + ws2[3];
    float mu  = s * (1.f / DMODEL);
    float var = s2 * (1.f / DMODEL) - mu * mu;
    float rs  = rsqrtf(var + 1e-5f);
    float4 gv = *(const float4*)(lng + tid * 4);
    float4 bv = *(const float4*)(lnb + tid * 4);
    ushort4 o;
    o.x = f2bf((v.x - mu) * rs * gv.x + bv.x);
    o.y = f2bf((v.y - mu) * rs * gv.y + bv.y);
    o.z = f2bf((v.z - mu) * rs * gv.z + bv.z);
    o.w = f2bf((v.w - mu) * rs * gv.w + bv.w);
    *(ushort4*)(xn + (size_t)t * DMODEL + tid * 4) = o;
  } else if (bid < PREP_T2) {
    // ---- fp32 [R][C] -> bf16 [C][R] transpose (32x32 tile per block)
    const float* in; ushort* out; int R, C, tb;
    if (bid < PREP_T1) { in = Wqkv; out = WqkvT; R = DMODEL; C = NQKV;   tb = bid - PREP_LN; }
    else               { in = Wout; out = WoutT; R = DMODEL; C = DMODEL; tb = bid - PREP_T1; }
    int ntx = C / 32;
    int c0 = (tb % ntx) * 32, r0 = (tb / ntx) * 32;
    int xx = tid & 31, yy = tid >> 5;
    __shared__ float tile[32][33];
#pragma unroll
    for (int i = 0; i < 32; i += 8) tile[yy + i][xx] = in[(size_t)(r0 + yy + i) * C + c0 + xx];
    __syncthreads();
#pragma unroll
    for (int i = 0; i < 32; i += 8)
      out[(size_t)(c0 + yy + i) * R + r0 + xx] = f2bf(tile[xx][yy + i]);
  } else {
    // ---- RoPE cos/sin tables: 4 rows per block
    int base = (bid - PREP_T2) * 4;
    int n = base + (tid >> 6), d = tid & 63;
    float invf = expf(-logf(10000.f) * (float)(d & 31) * (1.f / 32.f));
    float a = (float)n * invf;
    ct[n * DHEAD + d] = cosf(a);
    st[n * DHEAD + d] = sinf(a);
  }
}

// ---- GEMM: C[M][N] = A[M][K] * BT[N][K]^T; bf16 in. BK=32, 16KB LDS.
// Round-6/9 structure (best measured): 2-phase loop, slot-XOR swizzle (conflicts=0).
// LDS (row, slot) holds global (row, slot ^ ((row>>1)&3)); source pre-swizzled
// (gll16 dest linear, rule #21); fragment read XORs the same involution.
// EPI==1: RoPE + head-scatter epilogue (QKV GEMM) -> qh/kh/vh, q pre-scaled for exp2.
// EPI==2: fp32 + bias -> Cf (output projection).
template<int EPI>
__global__ __launch_bounds__(256) void gemm_bt(const ushort* __restrict__ A,
                                               const ushort* __restrict__ BT,
                                               float* __restrict__ Cf,
                                               const float* __restrict__ bias,
                                               ushort* __restrict__ qh,
                                               ushort* __restrict__ kh,
                                               ushort* __restrict__ vh,
                                               const float* __restrict__ ct,
                                               const float* __restrict__ st,
                                               int M, int N, int K) {
  __shared__ __align__(16) ushort As[128 * 32];
  __shared__ __align__(16) ushort Bs[128 * 32];
  int tid = threadIdx.x;
  int w = tid >> 6, lane = tid & 63;
  int lrow = lane & 15, g = lane >> 4;
  int m0 = blockIdx.y * 128, n0 = blockIdx.x * 128;
  int wr = (w >> 1) * 64, wc = (w & 1) * 64;
  int grow = lane >> 2;
  int gcol = ((lane & 3) ^ ((grow >> 1) & 3)) * 8;
  ushort* ldsA0 = As + w * 512;
  ushort* ldsA1 = As + 2048 + w * 512;
  ushort* ldsB0 = Bs + w * 512;
  ushort* ldsB1 = Bs + 2048 + w * 512;
  int fcol = (g ^ ((lrow >> 1) & 3)) * 8;
  f32x4 acc[4][4] = {};
  for (int k0 = 0; k0 < K; k0 += 32) {
    __syncthreads();
    GLL16(A  + (size_t)(m0 + w * 16 + grow) * K + k0 + gcol, ldsA0);
    GLL16(A  + (size_t)(m0 + 64 + w * 16 + grow) * K + k0 + gcol, ldsA1);
    GLL16(BT + (size_t)(n0 + w * 16 + grow) * K + k0 + gcol, ldsB0);
    GLL16(BT + (size_t)(n0 + 64 + w * 16 + grow) * K + k0 + gcol, ldsB1);
    __syncthreads();
    bf16x8 af[4], bfr[4];
#pragma unroll
    for (int i = 0; i < 4; i++) af[i]  = *(const bf16x8*)(As + (wr + i * 16 + lrow) * 32 + fcol);
#pragma unroll
    for (int i = 0; i < 4; i++) bfr[i] = *(const bf16x8*)(Bs + (wc + i * 16 + lrow) * 32 + fcol);
    __builtin_amdgcn_s_setprio(1);
#pragma unroll
    for (int mf = 0; mf < 4; mf++)
#pragma unroll
      for (int nf = 0; nf < 4; nf++)
        acc[mf][nf] = __builtin_amdgcn_mfma_f32_16x16x32_bf16(af[mf], bfr[nf], acc[mf][nf], 0, 0, 0);
    __builtin_amdgcn_s_setprio(0);
  }
#pragma unroll
  for (int mf = 0; mf < 4; mf++)
#pragma unroll
    for (int nf = 0; nf < 4; nf++) {
      int col = n0 + wc + nf * 16 + lrow;
#pragma unroll
      for (int r = 0; r < 4; r++) {
        int rowi = m0 + wr + mf * 16 + g * 4 + r;   // C/D: col=lane&15, row=4*(lane>>4)+reg
        float val = acc[mf][nf][r];
        if (EPI == 2) {
          Cf[(size_t)rowi * N + col] = val + bias[col];
        } else {
          int mat = col >> 10, c1 = col & 1023;
          int h = c1 >> 6, d = c1 & 63;
          int bb = rowi >> 11, n = rowi & (SEQ - 1);
          if (mat < 2) {
            float partner = acc[mf][nf ^ 2][r];     // col ^ 32 lives in the same lane
            float cs = ct[n * DHEAD + d], sn = st[n * DHEAD + d];
            float sgn = (d & 32) ? 1.f : -1.f;
            val = val * cs + sgn * partner * sn;
            if (mat == 0) val *= QK_SCALE;
          }
          ushort* dst = (mat == 0) ? qh : (mat == 1) ? kh : vh;
          dst[((size_t)(bb * HEADS + h) * SEQ + n) * DHEAD + d] = f2bf(val);
        }
      }
    }
}

// ---------------- causal flash attention (rd9 structure, unchanged) ----------------
// UN-PAIRED: block = (one 64-row q-tile, head); 1024 blocks = 4/CU. Descending-qt
// dispatch balances the triangular tail; heads grouped 4-per-XCD for K/V L2
// locality. Swapped QK^T (mfma(K,Q)) + kperm'd K rows => lane-local softmax.
__global__ __launch_bounds__(256) void attn_kernel(const ushort* __restrict__ q,
                                                   const ushort* __restrict__ k,
                                                   const ushort* __restrict__ v,
                                                   ushort* __restrict__ ao) {
  int wgid = blockIdx.x + gridDim.x * blockIdx.y;   // 0..1023
  int xcd = wgid & 7, idx = wgid >> 3;
  int bh = xcd * 4 + (idx & 3);          // 4 heads per XCD (K+V 2MB fits L2)
  int qt = 31 - (idx >> 2);              // big q-tiles dispatch first
  int tid = threadIdx.x, w = tid >> 6, lane = tid & 63;
  int lrow = lane & 15, g = lane >> 4;
  __shared__ __align__(16) ushort Ks[2][64 * 64];
  __shared__ __align__(16) ushort Vt[2][64 * 64];
  const ushort* qb = q + (size_t)bh * SEQ * DHEAD;
  const ushort* kb = k + (size_t)bh * SEQ * DHEAD;
  const ushort* vb = v + (size_t)bh * SEQ * DHEAD;
  const ushort* qp = qb + (size_t)(qt * 64 + w * 16 + lrow) * DHEAD + g * 8;
  bf16x8 qf0 = *(const bf16x8*)(qp), qf1 = *(const bf16x8*)(qp + 32);
  f32x4 aO[4] = {};
  float l_s = 0.f;

  int krow = tid >> 2, kco = (tid & 3) * 16;
  int pik = kperm(krow);
  int d0 = (tid & 31) * 2, kv8 = (tid >> 5) * 8;
  int4 ka0, ka1;
  unsigned int vd[8];

#define STAGE_ISSUE(j)                                                          \
  {                                                                             \
    const ushort* ks = kb + ((size_t)((j) * 64 + pik)) * DHEAD + kco;           \
    ka0 = *(const int4*)ks;                                                     \
    ka1 = *(const int4*)(ks + 8);                                               \
    const ushort* vs = vb + ((size_t)((j) * 64 + kv8)) * DHEAD + d0;            \
    _Pragma("unroll")                                                           \
    for (int jj = 0; jj < 8; jj++) vd[jj] = *(const unsigned int*)(vs + jj * DHEAD); \
  }

#define STAGE_WRITE(bsel)                                                       \
  {                                                                             \
    char* kd = (char*)Ks[bsel];                                                 \
    *(int4*)(kd + swz(krow, (tid & 3) * 32)) = ka0;                             \
    *(int4*)(kd + swz(krow, (tid & 3) * 32 + 16)) = ka1;                        \
    unsigned int lo[4], hi[4];                                                  \
    _Pragma("unroll")                                                           \
    for (int jj = 0; jj < 4; jj++) {                                            \
      lo[jj] = __builtin_amdgcn_perm(vd[2 * jj + 1], vd[2 * jj], 0x05040100u);  \
      hi[jj] = __builtin_amdgcn_perm(vd[2 * jj + 1], vd[2 * jj], 0x07060302u);  \
    }                                                                           \
    char* vdst = (char*)Vt[bsel];                                               \
    *(int4*)(vdst + swz(d0, kv8 * 2))     = *(int4*)lo;                         \
    *(int4*)(vdst + swz(d0 + 1, kv8 * 2)) = *(int4*)hi;                         \
  }

  STAGE_ISSUE(0);
  STAGE_WRITE(0);
  __syncthreads();
  int cur = 0;

  for (int jt = 0; jt <= qt; jt++) {
    if (jt < qt) STAGE_ISSUE(jt + 1);
    const char* kbuf = (const char*)Ks[cur];
    const char* vbuf = (const char*)Vt[cur];
    bf16x8 kf[8];
#pragma unroll
    for (int nf = 0; nf < 4; nf++) {
      kf[2 * nf]     = *(const bf16x8*)(kbuf + swz(nf * 16 + lrow, g * 16));
      kf[2 * nf + 1] = *(const bf16x8*)(kbuf + swz(nf * 16 + lrow, g * 16 + 64));
    }
    bf16x8 pa0, pa1;
    {
      f32x4 aS[4] = {};
      __builtin_amdgcn_s_setprio(1);
#pragma unroll
      for (int nf = 0; nf < 4; nf++) {
        aS[nf] = __builtin_amdgcn_mfma_f32_16x16x32_bf16(kf[2 * nf], qf0, aS[nf], 0, 0, 0);
        aS[nf] = __builtin_amdgcn_mfma_f32_16x16x32_bf16(kf[2 * nf + 1], qf1, aS[nf], 0, 0, 0);
      }
      __builtin_amdgcn_s_setprio(0);
      union { bf16x8 v; __hip_bfloat162 h[4]; } a0, a1;
      bool diag = (jt == qt);
#pragma unroll
      for (int nf = 0; nf < 4; nf++) {
        float p[4];
#pragma unroll
        for (int r = 0; r < 4; r++) {
          int kvl = (nf >> 1) * 32 + g * 8 + (nf & 1) * 4 + r;
          p[r] = exp2f(aS[nf][r]);
          if (diag && kvl > w * 16 + lrow) p[r] = 0.f;
          l_s += p[r];
        }
        __hip_bfloat162 plo = __float22bfloat162_rn({p[0], p[1]});
        __hip_bfloat162 phi = __float22bfloat162_rn({p[2], p[3]});
        if (nf < 2) { a0.h[(nf & 1) * 2] = plo; a0.h[(nf & 1) * 2 + 1] = phi; }
        else        { a1.h[(nf & 1) * 2] = plo; a1.h[(nf & 1) * 2 + 1] = phi; }
      }
      pa0 = a0.v; pa1 = a1.v;
    }
    bf16x8 vf[8];
#pragma unroll
    for (int nf = 0; nf < 4; nf++) {
      vf[2 * nf]     = *(const bf16x8*)(vbuf + swz(nf * 16 + lrow, g * 16));
      vf[2 * nf + 1] = *(const bf16x8*)(vbuf + swz(nf * 16 + lrow, g * 16 + 64));
    }
    __builtin_amdgcn_s_setprio(1);
#pragma unroll
    for (int nf = 0; nf < 4; nf++) {
      aO[nf] = __builtin_amdgcn_mfma_f32_16x16x32_bf16(pa0, vf[2 * nf], aO[nf], 0, 0, 0);
      aO[nf] = __builtin_amdgcn_mfma_f32_16x16x32_bf16(pa1, vf[2 * nf + 1], aO[nf], 0, 0, 0);
    }
    __builtin_amdgcn_s_setprio(0);
    if (jt < qt) STAGE_WRITE(cur ^ 1);
    __syncthreads();
    cur ^= 1;
  }

  l_s += __shfl_xor(l_s, 16);
  l_s += __shfl_xor(l_s, 32);
  int b = bh >> 4, h = bh & 15;
#pragma unroll
  for (int r = 0; r < 4; r++) {
    float inv = 1.f / __shfl(l_s, g * 4 + r);
#pragma unroll
    for (int nf = 0; nf < 4; nf++) {
      int col = h * DHEAD + nf * 16 + lrow;
      int tok = b * SEQ + qt * 64 + w * 16 + g * 4 + r;
      ao[(size_t)tok * DMODEL + col] = f2bf(aO[nf][r] * inv);
    }
  }
#undef STAGE_ISSUE
#undef STAGE_WRITE
}

extern "C" void kernel_launch(void* const* d_in, const int* in_sizes, int n_in,
                              void* d_out, int out_size, void* d_ws, size_t ws_size,
                              hipStream_t stream) {
  const float* x    = (const float*)d_in[0];
  const float* Wqkv = (const float*)d_in[1];
  const float* Wout = (const float*)d_in[2];
  const float* bout = (const float*)d_in[3];
  const float* lng  = (const float*)d_in[4];
  const float* lnb  = (const float*)d_in[5];
  float* out = (float*)d_out;

  ushort* xn    = (ushort*)d_ws;                       // reused as ao after QKV GEMM
  ushort* WqkvT = xn + (size_t)TOK * DMODEL;
  ushort* WoutT = WqkvT + (size_t)NQKV * DMODEL;
  ushort* qh    = WoutT + (size_t)DMODEL * DMODEL;
  ushort* kh    = qh + (size_t)BATCH * HEADS * SEQ * DHEAD;
  ushort* vh    = kh + (size_t)BATCH * HEADS * SEQ * DHEAD;
  float*  ct    = (float*)(vh + (size_t)BATCH * HEADS * SEQ * DHEAD);
  float*  st    = ct + SEQ * DHEAD;
  ushort* ao    = xn;

  hipLaunchKernelGGL(prep_kernel, dim3(PREP_TOTAL), dim3(256), 0, stream,
                     x, lng, lnb, xn, Wqkv, WqkvT, Wout, WoutT, ct, st);
  hipLaunchKernelGGL(gemm_bt<1>, dim3(NQKV / 128, TOK / 128), dim3(256), 0, stream,
                     xn, WqkvT, (float*)nullptr, (const float*)nullptr,
                     qh, kh, vh, ct, st, TOK, NQKV, DMODEL);
  hipLaunchKernelGGL(attn_kernel, dim3(32, 32), dim3(256), 0, stream,
                     qh, kh, vh, ao);
  hipLaunchKernelGGL(gemm_bt<2>, dim3(DMODEL / 128, TOK / 128), dim3(256), 0, stream,
                     ao, WoutT, out, bout,
                     (ushort*)nullptr, (ushort*)nullptr, (ushort*)nullptr,
                     (const float*)nullptr, (const float*)nullptr, TOK, DMODEL, DMODEL);
}